// Round 10
// baseline (1627.332 us; speedup 1.0000x reference)
//
#include <hip/hip_runtime.h>
#include <hip/hip_bf16.h>
#include <math.h>
#include <stdint.h>

// ---------------------------------------------------------------------------
// DiffusionCriterion, 3-kernel structure driven by round-9 counters:
//  * cost_kernel  (B*4 blocks x 128 thr): per-thread row softmax + 100 cost
//    entries written contiguously to ws + packed initial rowmin key + (mx+ls).
//    No register array -> no scratch spill (round-9: VGPR=84 < r[100]).
//  * match_kernel (B blocks x 64 thr = ONE WAVE): greedy matching with all
//    row-min keys in registers (8 u64/lane), per-step 6-shuffle butterfly,
//    ZERO barriers/LDS in the serial loop; rescans read contiguous rows from
//    ws (L2-resident). Losses computed in the same wave. Exact numpy
//    first-occurrence tie-break via (orderkey<<32|flatidx) u64 min.
//  * finalize_kernel: mean over batch.
// ---------------------------------------------------------------------------

#define QN 500
#define TN 100
#define CN 256
#define DIFFSTEPS 100
#define NPART 4
#define RPP 125      // rows per cost-kernel block

__device__ __forceinline__ float giou_xyxy(float ax1, float ay1, float ax2, float ay2,
                                           float bx1, float by1, float bx2, float by2) {
    float area1 = (ax2 - ax1) * (ay2 - ay1);
    float area2 = (bx2 - bx1) * (by2 - by1);
    float ltx = fmaxf(ax1, bx1), lty = fmaxf(ay1, by1);
    float rbx = fminf(ax2, bx2), rby = fminf(ay2, by2);
    float w = fmaxf(rbx - ltx, 0.f), h = fmaxf(rby - lty, 0.f);
    float inter = w * h;
    float uni = area1 + area2 - inter;
    float iou = inter / uni;
    float ex1 = fminf(ax1, bx1), ey1 = fminf(ay1, by1);
    float ex2 = fmaxf(ax2, bx2), ey2 = fmaxf(ay2, by2);
    float ew = fmaxf(ex2 - ex1, 0.f), eh = fmaxf(ey2 - ey1, 0.f);
    float ae = ew * eh;
    return iou - (ae - uni) / ae;
}

// Monotone order-preserving float->uint32 key (min float == min key).
__device__ __forceinline__ uint32_t fkey(float v) {
    uint32_t b = __float_as_uint(v);
    return (b & 0x80000000u) ? ~b : (b | 0x80000000u);
}

// ---------------- cost kernel ----------------
// grid = B*NPART blocks, 128 threads; thread owns one row (RPP rows/block).
__global__ __launch_bounds__(128) void cost_kernel(
    const float* __restrict__ logits, const float* __restrict__ boxes,
    const int* __restrict__ labels, const float* __restrict__ tboxes,
    float* __restrict__ Cmat, unsigned long long* __restrict__ keys,
    float* __restrict__ mxls) {

    const int bp = blockIdx.x;
    const int b = bp / NPART, part = bp - b * NPART;
    const int tid = threadIdx.x;

    __shared__ int    lbl_sh[TN];
    __shared__ float4 tb_sh[TN];
    if (tid < TN) {
        lbl_sh[tid] = labels[b * TN + tid];
        tb_sh[tid]  = *(const float4*)(tboxes + ((size_t)b * TN + tid) * 4);
    }
    __syncthreads();
    if (tid >= RPP) return;

    const int row = part * RPP + tid;
    const float* lrow = logits + ((size_t)b * QN + row) * CN;

    // 2-pass softmax stats (bit-identical to the round-9 passing kernel)
    float mx = -INFINITY;
    for (int c = 0; c < CN; c += 4) {
        float4 v = *(const float4*)(lrow + c);
        mx = fmaxf(mx, fmaxf(fmaxf(v.x, v.y), fmaxf(v.z, v.w)));
    }
    float se = 0.f;
    for (int c = 0; c < CN; c += 4) {
        float4 v = *(const float4*)(lrow + c);
        se += expf(v.x - mx) + expf(v.y - mx) + expf(v.z - mx) + expf(v.w - mx);
    }
    mxls[b * QN + row] = mx + logf(se);
    float inv = 1.f / se;

    float4 pb = *(const float4*)(boxes + ((size_t)b * QN + row) * 4);
    float ax1 = pb.x - 0.5f * pb.z, ay1 = pb.y - 0.5f * pb.w;
    float ax2 = pb.x + 0.5f * pb.z, ay2 = pb.y + 0.5f * pb.w;

    float* Crow = Cmat + ((size_t)b * QN + row) * TN;
    float bv = INFINITY; int ba = -1;
    float4 buf;
    #pragma unroll 4
    for (int t = 0; t < TN; ++t) {
        float4 tb = tb_sh[t];
        int   cls = lbl_sh[t];
        float e  = expf(lrow[cls] - mx);
        float cc = -(e * inv);
        float cb = fabsf(pb.x - tb.x) + fabsf(pb.y - tb.y) +
                   fabsf(pb.z - tb.z) + fabsf(pb.w - tb.w);
        float bx1 = tb.x - 0.5f * tb.z, by1 = tb.y - 0.5f * tb.w;
        float bx2 = tb.x + 0.5f * tb.z, by2 = tb.y + 0.5f * tb.w;
        float g  = giou_xyxy(ax1, ay1, ax2, ay2, bx1, by1, bx2, by2);
        float c  = cc + 5.f * cb - 2.f * g;
        ((float*)&buf)[t & 3] = c;
        if ((t & 3) == 3) *(float4*)(Crow + (t - 3)) = buf;
        if (c < bv) { bv = c; ba = t; }          // strict <: first occurrence
    }
    keys[b * QN + row] =
        ((unsigned long long)fkey(bv) << 32) | (unsigned long long)(row * TN + ba);
}

// ---------------- match + loss kernel: ONE wave per image ----------------
__global__ __launch_bounds__(64) void match_kernel(
    const float* __restrict__ logits, const float* __restrict__ boxes,
    const int* __restrict__ labels, const float* __restrict__ tboxes,
    const int* __restrict__ ttime, const float* __restrict__ noise,
    const float* __restrict__ Cmat, const unsigned long long* __restrict__ keys,
    const float* __restrict__ mxls, float* __restrict__ per_img) {

    const int b = blockIdx.x;
    const int l = threadIdx.x;   // 0..63

    // lane l owns rows {s*64 + l : s=0..7, row<QN}; keys in registers
    unsigned long long k8[8];
    int a8[8];
    #pragma unroll
    for (int s = 0; s < 8; ++s) {
        int row = s * 64 + l;
        if (row < QN) {
            unsigned long long kk = keys[b * QN + row];
            k8[s] = kk;
            a8[s] = (int)(kk & 0xFFFFFFFFull) - row * TN;   // argmin col
        } else { k8[s] = ~0ull; a8[s] = -1; }
    }

    unsigned long long m0 = ~0ull, m1 = ~0ull;  // alive-col bitmask (0..63 / 64..99)
    int pi0 = -1, pj0 = -1, pi1 = -1, pj1 = -1; // this lane's recorded pairs

    for (int k = 0; k < TN; ++k) {
        // local min over 8 slots (register chain, exact u64 tie-break)
        unsigned long long pk = k8[0];
        #pragma unroll
        for (int s = 1; s < 8; ++s) pk = (k8[s] < pk) ? k8[s] : pk;
        // wave butterfly min — no barrier, no LDS
        #pragma unroll
        for (int o = 1; o < 64; o <<= 1) {
            unsigned long long q = __shfl_xor(pk, o, 64);
            pk = (q < pk) ? q : pk;
        }
        int flat = (int)(pk & 0xFFFFFFFFull);
        int is = flat / TN;
        int js = flat - is * TN;

        if ((k & 63) == l) {                     // record pair for loss phase
            if (k < 64) { pi0 = is; pj0 = js; } else { pi1 = is; pj1 = js; }
        }
        if (js < 64) m0 &= ~(1ull << js); else m1 &= ~(1ull << (js - 64));
        int os = is >> 6;
        if ((is & 63) == l) { k8[os] = ~0ull; a8[os] = -1; }   // kill row

        // rescan any of my rows whose argmin column just died
        #pragma unroll
        for (int s = 0; s < 8; ++s) {
            if (a8[s] == js) {
                int row = s * 64 + l;
                const float* Crow = Cmat + ((size_t)b * QN + row) * TN;
                float nbv = INFINITY; int nba = -1;
                #pragma unroll
                for (int j4 = 0; j4 < TN / 4; ++j4) {
                    float4 v = *(const float4*)(Crow + j4 * 4);
                    #pragma unroll
                    for (int e = 0; e < 4; ++e) {
                        int jj = j4 * 4 + e;
                        bool ok = (jj < 64) ? (((m0 >> jj) & 1ull) != 0ull)
                                            : (((m1 >> (jj - 64)) & 1ull) != 0ull);
                        float c = ((const float*)&v)[e];
                        if (ok && (c < nbv)) { nbv = c; nba = jj; }
                    }
                }
                k8[s] = ((unsigned long long)fkey(nbv) << 32) |
                        (unsigned long long)(uint32_t)(row * TN + nba);
                a8[s] = nba;
            }
        }
    }

    // ---- losses (same wave) ----
    int t = ttime[b];
    float step = (0.02f - 1e-4f) / (float)(DIFFSTEPS - 1);
    float acp = 1.f;
    for (int i2 = 0; i2 <= t; ++i2) acp *= (1.f - (1e-4f + step * (float)i2));
    float scale = sqrtf(1.f - acp);

    float contrib = 0.f;
    #pragma unroll
    for (int rnd = 0; rnd < 2; ++rnd) {
        int i = rnd ? pi1 : pi0, j = rnd ? pj1 : pj0;
        if (rnd == 0 || l < TN - 64) {
            int cls = labels[b * TN + j];
            float lc = logits[((size_t)b * QN + i) * CN + cls];
            float ce = mxls[b * QN + i] - lc;    // == -(lc - mx - ls)

            float4 sb = *(const float4*)(boxes + ((size_t)b * QN + i) * 4);
            float4 gb = *(const float4*)(tboxes + ((size_t)b * TN + j) * 4);
            float bb = fabsf(sb.x - gb.x) + fabsf(sb.y - gb.y) +
                       fabsf(sb.z - gb.z) + fabsf(sb.w - gb.w);

            float ax1 = sb.x - 0.5f * sb.z, ay1 = sb.y - 0.5f * sb.w;
            float ax2 = sb.x + 0.5f * sb.z, ay2 = sb.y + 0.5f * sb.w;
            float bx1 = gb.x - 0.5f * gb.z, by1 = gb.y - 0.5f * gb.w;
            float bx2 = gb.x + 0.5f * gb.z, by2 = gb.y + 0.5f * gb.w;
            float gi = giou_xyxy(ax1, ay1, ax2, ay2, bx1, by1, bx2, by2);

            float4 nz = *(const float4*)(noise + ((size_t)b * TN + j) * 4);
            float d0 = sb.x - (gb.x + nz.x * scale), d1 = sb.y - (gb.y + nz.y * scale);
            float d2 = sb.z - (gb.z + nz.z * scale), d3 = sb.w - (gb.w + nz.w * scale);
            float df = d0 * d0 + d1 * d1 + d2 * d2 + d3 * d3;

            contrib += ce + 5.f * bb - 2.f * gi + 0.25f * df;
        }
    }
    #pragma unroll
    for (int o = 1; o < 64; o <<= 1) contrib += __shfl_xor(contrib, o, 64);
    if (l == 0) per_img[b] = 2.0f + contrib / (float)TN;
}

__global__ void finalize_kernel(const float* __restrict__ per_img, float* __restrict__ out, int B) {
    __shared__ float red[256];
    int tid = threadIdx.x;
    float v = (tid < B) ? per_img[tid] : 0.f;
    red[tid] = v;
    __syncthreads();
    for (int s = 128; s > 0; s >>= 1) {
        if (tid < s) red[tid] += red[tid + s];
        __syncthreads();
    }
    if (tid == 0) out[0] = red[0] / (float)B;
}

extern "C" void kernel_launch(void* const* d_in, const int* in_sizes, int n_in,
                              void* d_out, int out_size, void* d_ws, size_t ws_size,
                              hipStream_t stream) {
    const float* pred_logits = (const float*)d_in[0];
    const float* pred_boxes  = (const float*)d_in[1];
    const int*   tgt_labels  = (const int*)d_in[2];
    const float* tgt_boxes   = (const float*)d_in[3];
    const int*   tgt_time    = (const int*)d_in[4];
    const float* noise       = (const float*)d_in[5];
    float* out = (float*)d_out;

    const int B = in_sizes[4];                   // tgt_time: [B]

    // ws layout: Cmat | keys | mxls | per_img
    float* Cmat = (float*)d_ws;                                  // B*QN*TN f32
    unsigned long long* keys =
        (unsigned long long*)((char*)d_ws + (size_t)B * QN * TN * 4); // B*QN u64
    float* mxls = (float*)((char*)keys + (size_t)B * QN * 8);    // B*QN f32
    float* per_img = mxls + (size_t)B * QN;                      // B f32

    cost_kernel<<<B * NPART, 128, 0, stream>>>(pred_logits, pred_boxes, tgt_labels,
                                               tgt_boxes, Cmat, keys, mxls);
    match_kernel<<<B, 64, 0, stream>>>(pred_logits, pred_boxes, tgt_labels,
                                       tgt_boxes, tgt_time, noise,
                                       Cmat, keys, mxls, per_img);
    finalize_kernel<<<1, 256, 0, stream>>>(per_img, out, B);
}

// Round 13
// 418.605 us; speedup vs baseline: 3.8875x; 3.8875x over previous
//
#include <hip/hip_runtime.h>
#include <hip/hip_bf16.h>
#include <math.h>
#include <stdint.h>

// ---------------------------------------------------------------------------
// Fully-fused DiffusionCriterion (round-9 structure, spill fixed).
// One block (512 threads) per image. Thread i (< Q=500) owns cost-matrix row i
// in REGISTERS (r[100], fully unrolled). __launch_bounds__(512,2) raises the
// VGPR cap to 256 so r[100] stays in registers (round-9 measured VGPR=84 ->
// scratch spill -> 240MB FETCH; round-10 single-wave variant was worse).
// Greedy matching: T=100 sequential steps, wave shuffle-butterfly argmin on
// packed (orderkey|flatidx) u64, one LDS hop across 8 waves (parity
// double-buffered -> 1 barrier/step), register-resident rescan vs a 2x u64
// alive-column bitmask. Exact numpy first-occurrence tie-break.
// ---------------------------------------------------------------------------

#define QN 500
#define TN 100
#define CN 256
#define DIFFSTEPS 100
#define NTHR 512

__device__ __forceinline__ float giou_xyxy(float ax1, float ay1, float ax2, float ay2,
                                           float bx1, float by1, float bx2, float by2) {
    float area1 = (ax2 - ax1) * (ay2 - ay1);
    float area2 = (bx2 - bx1) * (by2 - by1);
    float ltx = fmaxf(ax1, bx1), lty = fmaxf(ay1, by1);
    float rbx = fminf(ax2, bx2), rby = fminf(ay2, by2);
    float w = fmaxf(rbx - ltx, 0.f), h = fmaxf(rby - lty, 0.f);
    float inter = w * h;
    float uni = area1 + area2 - inter;
    float iou = inter / uni;
    float ex1 = fminf(ax1, bx1), ey1 = fminf(ay1, by1);
    float ex2 = fmaxf(ax2, bx2), ey2 = fmaxf(ay2, by2);
    float ew = fmaxf(ex2 - ex1, 0.f), eh = fmaxf(ey2 - ey1, 0.f);
    float ae = ew * eh;
    return iou - (ae - uni) / ae;
}

// Monotone order-preserving float->uint32 key (min float == min key).
__device__ __forceinline__ uint32_t fkey(float v) {
    uint32_t b = __float_as_uint(v);
    return (b & 0x80000000u) ? ~b : (b | 0x80000000u);
}

__global__ __launch_bounds__(NTHR, 2) void fused_match_kernel(
    const float* __restrict__ logits, const float* __restrict__ boxes,
    const int* __restrict__ labels, const float* __restrict__ tboxes,
    const int* __restrict__ ttime, const float* __restrict__ noise,
    float* __restrict__ per_img) {

    const int b = blockIdx.x;
    const int tid = threadIdx.x;

    __shared__ int    lbl_sh[TN];
    __shared__ float4 tb_sh[TN];
    __shared__ float  mx_sh[QN];
    __shared__ float  ls_sh[QN];
    __shared__ int    srcS[TN], tgtS[TN];
    __shared__ unsigned long long wmin[2][8];   // parity double-buffer
    __shared__ float  pSum[8];
    __shared__ float  s_scale;

    // ---- stage targets + diffusion scale ----
    if (tid < TN) {
        lbl_sh[tid] = labels[b * TN + tid];
        tb_sh[tid]  = *(const float4*)(tboxes + ((size_t)b * TN + tid) * 4);
    }
    if (tid == NTHR - 1) {
        int t = ttime[b];
        float step = (0.02f - 1e-4f) / (float)(DIFFSTEPS - 1);
        float acp = 1.f;
        for (int i2 = 0; i2 <= t; ++i2) acp *= (1.f - (1e-4f + step * (float)i2));
        s_scale = sqrtf(1.f - acp);
    }
    __syncthreads();

    // ---- per-thread row build (registers) ----
    float r[TN];
    bool  alive  = (tid < QN);
    uint32_t mykey  = 0xFFFFFFFFu;
    uint32_t myflat = 0xFFFFFFFFu;
    int   myarg = -1;

    if (alive) {
        const float* lrow = logits + ((size_t)b * QN + tid) * CN;
        float mx = -INFINITY;
        for (int c = 0; c < CN; c += 4) {
            float4 v = *(const float4*)(lrow + c);
            mx = fmaxf(mx, fmaxf(fmaxf(v.x, v.y), fmaxf(v.z, v.w)));
        }
        float se = 0.f;
        for (int c = 0; c < CN; c += 4) {
            float4 v = *(const float4*)(lrow + c);
            se += expf(v.x - mx) + expf(v.y - mx) + expf(v.z - mx) + expf(v.w - mx);
        }
        mx_sh[tid] = mx;
        ls_sh[tid] = logf(se);
        float inv = 1.f / se;

        float4 pb = *(const float4*)(boxes + ((size_t)b * QN + tid) * 4);
        float ax1 = pb.x - 0.5f * pb.z, ay1 = pb.y - 0.5f * pb.w;
        float ax2 = pb.x + 0.5f * pb.z, ay2 = pb.y + 0.5f * pb.w;

        float bv = INFINITY; int ba = -1;
        #pragma unroll
        for (int t = 0; t < TN; ++t) {
            float4 tb = tb_sh[t];
            int   cls = lbl_sh[t];
            float e  = expf(lrow[cls] - mx);
            float cc = -(e * inv);
            float cb = fabsf(pb.x - tb.x) + fabsf(pb.y - tb.y) +
                       fabsf(pb.z - tb.z) + fabsf(pb.w - tb.w);
            float bx1 = tb.x - 0.5f * tb.z, by1 = tb.y - 0.5f * tb.w;
            float bx2 = tb.x + 0.5f * tb.z, by2 = tb.y + 0.5f * tb.w;
            float g  = giou_xyxy(ax1, ay1, ax2, ay2, bx1, by1, bx2, by2);
            float c  = cc + 5.f * cb - 2.f * g;
            r[t] = c;
            if (c < bv) { bv = c; ba = t; }     // strict <: first occurrence
        }
        myarg  = ba;
        mykey  = fkey(bv);
        myflat = (uint32_t)(tid * TN + ba);
    }

    unsigned long long m0 = ~0ull, m1 = ~0ull;  // alive-column bitmask

    // ---- greedy matching: TN sequential steps, 1 barrier each ----
    for (int k = 0; k < TN; ++k) {
        unsigned long long pk = ((unsigned long long)mykey << 32) | (unsigned long long)myflat;
        #pragma unroll
        for (int o = 1; o < 64; o <<= 1) {
            unsigned long long q = __shfl_xor(pk, o, 64);
            pk = (q < pk) ? q : pk;
        }
        if ((tid & 63) == 0) wmin[k & 1][tid >> 6] = pk;
        __syncthreads();
        unsigned long long best = wmin[k & 1][0];
        #pragma unroll
        for (int w = 1; w < 8; ++w) {
            unsigned long long q = wmin[k & 1][w];
            best = (q < best) ? q : best;
        }
        uint32_t flat = (uint32_t)best;
        int is = (int)(flat / TN);
        int js = (int)(flat - (uint32_t)is * TN);

        if (tid == is) {                        // unique winner records the pair
            srcS[k] = is; tgtS[k] = js;
            alive = false; mykey = 0xFFFFFFFFu; myflat = 0xFFFFFFFFu;
        }
        if (js < 64) m0 &= ~(1ull << js); else m1 &= ~(1ull << (js - 64));

        if (alive && myarg == js) {             // register-resident rescan
            float nbv = INFINITY; int nba = -1;
            #pragma unroll
            for (int jj = 0; jj < TN; ++jj) {
                bool ok = (jj < 64) ? (((m0 >> jj) & 1ull) != 0ull)
                                    : (((m1 >> (jj - 64)) & 1ull) != 0ull);
                float c = r[jj];
                if (ok && (c < nbv)) { nbv = c; nba = jj; }
            }
            myarg  = nba;
            mykey  = fkey(nbv);
            myflat = (uint32_t)(tid * TN + nba);
        }
        // parity double-buffer on wmin: barrier at k+1 separates this step's
        // reads of wmin[k&1] from the overwrite at step k+2.
    }
    __syncthreads();

    // ---- losses: one thread per matched pair ----
    float contrib = 0.f;
    if (tid < TN) {
        int i = srcS[tid], j = tgtS[tid];
        int cls = lbl_sh[j];
        float lc = logits[((size_t)b * QN + i) * CN + cls];
        float ce = -(lc - mx_sh[i] - ls_sh[i]);

        float4 sb = *(const float4*)(boxes + ((size_t)b * QN + i) * 4);
        float4 gb = tb_sh[j];
        float bb = fabsf(sb.x - gb.x) + fabsf(sb.y - gb.y) +
                   fabsf(sb.z - gb.z) + fabsf(sb.w - gb.w);

        float ax1 = sb.x - 0.5f * sb.z, ay1 = sb.y - 0.5f * sb.w;
        float ax2 = sb.x + 0.5f * sb.z, ay2 = sb.y + 0.5f * sb.w;
        float bx1 = gb.x - 0.5f * gb.z, by1 = gb.y - 0.5f * gb.w;
        float bx2 = gb.x + 0.5f * gb.z, by2 = gb.y + 0.5f * gb.w;
        float gi = giou_xyxy(ax1, ay1, ax2, ay2, bx1, by1, bx2, by2);

        float4 nz = *(const float4*)(noise + ((size_t)b * TN + j) * 4);
        float sc = s_scale;
        float d0 = sb.x - (gb.x + nz.x * sc), d1 = sb.y - (gb.y + nz.y * sc);
        float d2 = sb.z - (gb.z + nz.z * sc), d3 = sb.w - (gb.w + nz.w * sc);
        float df = d0 * d0 + d1 * d1 + d2 * d2 + d3 * d3;

        // loss = ce/T*1 + bb/T*5 + 2*(1 - gi_sum/T) + df_sum/(4T)
        contrib = ce + 5.f * bb - 2.f * gi + 0.25f * df;
    }
    #pragma unroll
    for (int o = 1; o < 64; o <<= 1) contrib += __shfl_xor(contrib, o, 64);
    if ((tid & 63) == 0) pSum[tid >> 6] = contrib;
    __syncthreads();
    if (tid == 0) {
        float tot = 0.f;
        for (int w = 0; w < 8; ++w) tot += pSum[w];
        per_img[b] = 2.0f + tot / (float)TN;
    }
}

__global__ void finalize_kernel(const float* __restrict__ per_img, float* __restrict__ out, int B) {
    __shared__ float red[256];
    int tid = threadIdx.x;
    float v = (tid < B) ? per_img[tid] : 0.f;
    red[tid] = v;
    __syncthreads();
    for (int s = 128; s > 0; s >>= 1) {
        if (tid < s) red[tid] += red[tid + s];
        __syncthreads();
    }
    if (tid == 0) out[0] = red[0] / (float)B;
}

extern "C" void kernel_launch(void* const* d_in, const int* in_sizes, int n_in,
                              void* d_out, int out_size, void* d_ws, size_t ws_size,
                              hipStream_t stream) {
    const float* pred_logits = (const float*)d_in[0];
    const float* pred_boxes  = (const float*)d_in[1];
    const int*   tgt_labels  = (const int*)d_in[2];
    const float* tgt_boxes   = (const float*)d_in[3];
    const int*   tgt_time    = (const int*)d_in[4];
    const float* noise       = (const float*)d_in[5];
    float* out = (float*)d_out;

    const int B = in_sizes[4];                   // tgt_time: [B]
    float* per_img = (float*)d_ws;               // B floats of scratch

    fused_match_kernel<<<B, NTHR, 0, stream>>>(pred_logits, pred_boxes, tgt_labels,
                                               tgt_boxes, tgt_time, noise, per_img);
    finalize_kernel<<<1, 256, 0, stream>>>(per_img, out, B);
}